// Round 14
// baseline (122.853 us; speedup 1.0000x reference)
//
#include <hip/hip_runtime.h>

#define DIN 512
#define DOUT 512

typedef int v4i __attribute__((ext_vector_type(4)));
typedef float v4f __attribute__((ext_vector_type(4)));

// exact-divide quantize (weights/bias path, matches ref bit-for-bit)
__device__ __forceinline__ int q8f(float v, float s) {
    int i = (int)rintf(v / s);
    i = i < -128 ? -128 : (i > 127 ? 127 : i);
    return i & 255;
}
// multiply-by-reciprocal quantize (activation path; flip prob ~2^-22, contribution ~0.005 << 0.0525)
__device__ __forceinline__ int q8m(float v, float inv) {
    int i = (int)rintf(v * inv);
    i = i < -128 ? -128 : (i > 127 ? 127 : i);
    return i & 255;
}

// ---------------- Kernel 1: global absmax of x ----------------
__global__ void absmax_kernel(const float4* __restrict__ x4, unsigned* __restrict__ amax, int n4) {
    float m = 0.f;
    int stride = gridDim.x * blockDim.x;
    for (int i = blockIdx.x * blockDim.x + threadIdx.x; i < n4; i += stride) {
        float4 v = x4[i];
        m = fmaxf(m, fmaxf(fmaxf(fabsf(v.x), fabsf(v.y)), fmaxf(fabsf(v.z), fabsf(v.w))));
    }
#pragma unroll
    for (int off = 32; off; off >>= 1) m = fmaxf(m, __shfl_xor(m, off));
    __shared__ float sm[4];
    int lane = threadIdx.x & 63, w = threadIdx.x >> 6;
    if (lane == 0) sm[w] = m;
    __syncthreads();
    if (threadIdx.x == 0) {
        m = fmaxf(fmaxf(sm[0], sm[1]), fmaxf(sm[2], sm[3]));
        atomicMax(amax, __float_as_uint(m));  // positive floats: uint compare == float compare
    }
}

// ---------------- Kernel 2: weight quant -> frag-linear wq8 (+ amax zero-init) ----------------
// wq8 byte(og,ks,kq,r,b) = og*8192 + ks*1024 + kq*256 + r*16 + b ==> a wave's
// A-frag (og,ks) is CONTIGUOUS 1KB at wq8 + og*8192 + ks*1024 + lane*16. (R12-validated)
__global__ void quantw_kernel(const float* __restrict__ w, char* __restrict__ wq8,
                              float* __restrict__ wsc, unsigned* __restrict__ amax) {
    int gid = blockIdx.x * blockDim.x + threadIdx.x;
    if (gid == 0) *amax = 0u;   // zero-init; absmax launches after quantw on same stream
    int row = gid >> 6, lane = gid & 63;
    const float4* r4 = (const float4*)(w + (long)row * DIN);
    float4 a = r4[lane * 2];
    float4 b = r4[lane * 2 + 1];
    float m = fmaxf(fmaxf(fmaxf(fabsf(a.x), fabsf(a.y)), fabsf(a.z)),
                    fmaxf(fmaxf(fabsf(a.w), fabsf(b.x)),
                          fmaxf(fmaxf(fabsf(b.y), fabsf(b.z)), fabsf(b.w))));
#pragma unroll
    for (int off = 32; off; off >>= 1) m = fmaxf(m, __shfl_xor(m, off));
    float s = m / 127.0f;
    int lo = q8f(a.x, s) | (q8f(a.y, s) << 8) | (q8f(a.z, s) << 16) | (q8f(a.w, s) << 24);
    int hi = q8f(b.x, s) | (q8f(b.y, s) << 8) | (q8f(b.z, s) << 16) | (q8f(b.w, s) << 24);
    {
        int og = row >> 4, r = row & 15;
        int ks = lane >> 3, kq = (lane >> 1) & 3, bo = (lane & 1) * 8;
        *(int2*)(wq8 + og * 8192 + ks * 1024 + kq * 256 + r * 16 + bo) = make_int2(lo, hi);
    }
    if (lane == 0) wsc[row] = s;
}

// ---------------- Kernel 2c: quantize x -> chunk-linear int8 (R12-validated) ----------------
// x8 byte(T,ks,c,kq,r) = T*32768 + ks*4096 + c*1024 + kq*256 + r*16.
// Thread g: reads 64B contiguous fp32 of row T*64+c*16+r at col ks*64+kq*16,
// writes ONE 16B line at x8+g*16 -> wave writes perfectly lane-linear 1KB/instr.
__global__ __launch_bounds__(512) void quantx_kernel(
    const float* __restrict__ x, const unsigned* __restrict__ amax,
    char* __restrict__ x8) {
    const long g = (long)blockIdx.x * 512 + threadIdx.x;
    const float inv_as = 1.0f / (__uint_as_float(*amax) / 127.0f);
    const long T = g >> 11;
    const int L = (int)(g & 2047);
    const int ks = L >> 8, c = (L >> 6) & 3, kq = (L >> 4) & 3, r = L & 15;
    const float4* src = (const float4*)(x + (T * 64 + c * 16 + r) * DIN + ks * 64 + kq * 16);
    float4 v0 = src[0], v1 = src[1], v2 = src[2], v3 = src[3];
    v4i q;
    q[0] = q8m(v0.x, inv_as) | (q8m(v0.y, inv_as) << 8) | (q8m(v0.z, inv_as) << 16) | (q8m(v0.w, inv_as) << 24);
    q[1] = q8m(v1.x, inv_as) | (q8m(v1.y, inv_as) << 8) | (q8m(v1.z, inv_as) << 16) | (q8m(v1.w, inv_as) << 24);
    q[2] = q8m(v2.x, inv_as) | (q8m(v2.y, inv_as) << 8) | (q8m(v2.z, inv_as) << 16) | (q8m(v2.w, inv_as) << 24);
    q[3] = q8m(v3.x, inv_as) | (q8m(v3.y, inv_as) << 8) | (q8m(v3.z, inv_as) << 16) | (q8m(v3.w, inv_as) << 24);
    *(v4i*)(x8 + g * 16) = q;
}

// ---------------- Kernel 3: SLIM barrier-free per-wave int8 GEMM ----------------
// 512 blocks x 256 thr (4 waves), __launch_bounds__(256,3) -> 3 waves/SIMD
// (12 waves/CU) — the occupancy lever vs R12/R13's 2. Per-wave state is
// minimal: xa[2][8] int8 frags (64 VGPR, loaded once from L3-hot x8, contiguous
// 1KB each), single-buffered wf[8] (32 VGPR) streamed from L2-resident wq8,
// 4 accumulation chains (16), addr/misc (~25) => ~140 VGPR, no spill.
// Per og: 8 contiguous 1KB loads + 16 MFMA + scale/bias + 2 normal v4f stores.
// No barriers after prologue; 3-wave TLP hides the single-buffer L2 latency.
__global__ __launch_bounds__(256, 3) void gemm_kernel(
    const char* __restrict__ x8, const char* __restrict__ wq8,
    const float* __restrict__ wsc, const float* __restrict__ bias,
    const unsigned* __restrict__ amax, float* __restrict__ out) {
    __shared__ __align__(16) float bsl[512];
    __shared__ __align__(16) float bql[512];
    const int t = threadIdx.x, lane = t & 63, wid = t >> 6;
    const float as = __uint_as_float(*amax) / 127.0f;

    // fold quantb: two oc per thread
    {
        float s0 = as * wsc[t];
        bsl[t] = s0;
        bql[t] = rintf(bias[t] / s0) * s0;
        float s1 = as * wsc[t + 256];
        bsl[t + 256] = s1;
        bql[t + 256] = rintf(bias[t + 256] / s1) * s1;
    }
    __syncthreads();   // the only barrier

    const int gw = (gridDim.x - 1 - blockIdx.x) * 4 + wid;   // reverse: x8 L2/L3 recency
    const long m0 = (long)gw * 32;
    const char* xt = x8 + (long)(gw >> 1) * 32768 + (gw & 1) * 2048 + lane * 16;
    const char* wg = wq8 + lane * 16;
    const int bo = (lane >> 4) * 4;                      // oc sub-offset
    float* outr = out + (m0 + (lane & 15)) * DOUT + bo;  // mi=0 row base

    v4i xa[2][8];
#pragma unroll
    for (int ks = 0; ks < 8; ks++) {
        xa[0][ks] = *(const v4i*)(xt + ks * 4096);
        xa[1][ks] = *(const v4i*)(xt + ks * 4096 + 1024);
    }

#pragma unroll 1
    for (int og = 0; og < 32; og++) {
        v4i wf[8];
#pragma unroll
        for (int ks = 0; ks < 8; ks++)
            wf[ks] = *(const v4i*)(wg + og * 8192 + ks * 1024);
        v4i a00, a01, a10, a11;
        const v4i Z = {0, 0, 0, 0};
        a00 = __builtin_amdgcn_mfma_i32_16x16x64_i8(wf[0], xa[0][0], Z, 0, 0, 0);
        a10 = __builtin_amdgcn_mfma_i32_16x16x64_i8(wf[0], xa[1][0], Z, 0, 0, 0);
        a01 = __builtin_amdgcn_mfma_i32_16x16x64_i8(wf[1], xa[0][1], Z, 0, 0, 0);
        a11 = __builtin_amdgcn_mfma_i32_16x16x64_i8(wf[1], xa[1][1], Z, 0, 0, 0);
#pragma unroll
        for (int kp = 2; kp < 8; kp += 2) {
            a00 = __builtin_amdgcn_mfma_i32_16x16x64_i8(wf[kp], xa[0][kp], a00, 0, 0, 0);
            a10 = __builtin_amdgcn_mfma_i32_16x16x64_i8(wf[kp], xa[1][kp], a10, 0, 0, 0);
            a01 = __builtin_amdgcn_mfma_i32_16x16x64_i8(wf[kp + 1], xa[0][kp + 1], a01, 0, 0, 0);
            a11 = __builtin_amdgcn_mfma_i32_16x16x64_i8(wf[kp + 1], xa[1][kp + 1], a11, 0, 0, 0);
        }
        v4i s0 = a00 + a01, s1 = a10 + a11;
        float4 s4 = *(const float4*)&bsl[og * 16 + bo];
        float4 q4 = *(const float4*)&bql[og * 16 + bo];
        v4f v0, v1;
        v0[0] = (float)s0[0] * s4.x + q4.x; v0[1] = (float)s0[1] * s4.y + q4.y;
        v0[2] = (float)s0[2] * s4.z + q4.z; v0[3] = (float)s0[3] * s4.w + q4.w;
        v1[0] = (float)s1[0] * s4.x + q4.x; v1[1] = (float)s1[1] * s4.y + q4.y;
        v1[2] = (float)s1[2] * s4.z + q4.z; v1[3] = (float)s1[3] * s4.w + q4.w;
        *(v4f*)(outr + og * 16) = v0;
        *(v4f*)(outr + 16 * DOUT + og * 16) = v1;
    }
}

extern "C" void kernel_launch(void* const* d_in, const int* in_sizes, int n_in,
                              void* d_out, int out_size, void* d_ws, size_t ws_size,
                              hipStream_t stream) {
    const float* x    = (const float*)d_in[0];
    const float* w    = (const float*)d_in[1];
    const float* bias = (const float*)d_in[2];
    float* out = (float*)d_out;
    const int M = in_sizes[0] / DIN;   // 65536

    char* ws = (char*)d_ws;
    unsigned* amax = (unsigned*)ws;
    char* wq8  = ws + 64;
    float* wsc = (float*)(wq8 + (long)DOUT * DIN);
    char* x8   = (char*)(wsc + DOUT);

    quantw_kernel<<<(DOUT * 64) / 256, 256, 0, stream>>>(w, wq8, wsc, amax);
    absmax_kernel<<<2048, 256, 0, stream>>>((const float4*)x, amax, in_sizes[0] / 4);
    quantx_kernel<<<(M * DIN / 16) / 512, 512, 0, stream>>>(x, amax, x8);
    gemm_kernel<<<M / 128, 256, 0, stream>>>(x8, wq8, wsc, bias, amax, out);
}

// Round 15
// 100.599 us; speedup vs baseline: 1.2212x; 1.2212x over previous
//
#include <hip/hip_runtime.h>

#define DIN 512
#define DOUT 512

typedef int v4i __attribute__((ext_vector_type(4)));
typedef float v4f __attribute__((ext_vector_type(4)));

// exact-divide quantize (weights/bias path, matches ref bit-for-bit)
__device__ __forceinline__ int q8f(float v, float s) {
    int i = (int)rintf(v / s);
    i = i < -128 ? -128 : (i > 127 ? 127 : i);
    return i & 255;
}
// multiply-by-reciprocal quantize (activation path; flip prob ~2^-22, contribution ~0.005 << 0.0525)
__device__ __forceinline__ int q8m(float v, float inv) {
    int i = (int)rintf(v * inv);
    i = i < -128 ? -128 : (i > 127 ? 127 : i);
    return i & 255;
}

// ---------------- Kernel 1: global absmax of x ----------------
__global__ void absmax_kernel(const float4* __restrict__ x4, unsigned* __restrict__ amax, int n4) {
    float m = 0.f;
    int stride = gridDim.x * blockDim.x;
    for (int i = blockIdx.x * blockDim.x + threadIdx.x; i < n4; i += stride) {
        float4 v = x4[i];
        m = fmaxf(m, fmaxf(fmaxf(fabsf(v.x), fabsf(v.y)), fmaxf(fabsf(v.z), fabsf(v.w))));
    }
#pragma unroll
    for (int off = 32; off; off >>= 1) m = fmaxf(m, __shfl_xor(m, off));
    __shared__ float sm[4];
    int lane = threadIdx.x & 63, w = threadIdx.x >> 6;
    if (lane == 0) sm[w] = m;
    __syncthreads();
    if (threadIdx.x == 0) {
        m = fmaxf(fmaxf(sm[0], sm[1]), fmaxf(sm[2], sm[3]));
        atomicMax(amax, __float_as_uint(m));  // positive floats: uint compare == float compare
    }
}

// ---------------- Kernel 2: weight quant -> frag-linear wq8 (+ amax zero-init) ----------------
// wq8 byte(og,ks,kq,r,b) = og*8192 + ks*1024 + kq*256 + r*16 + b ==> a wave's
// A-frag (og,ks) is CONTIGUOUS 1KB at wq8 + og*8192 + ks*1024 + lane*16. (R12-validated)
__global__ void quantw_kernel(const float* __restrict__ w, char* __restrict__ wq8,
                              float* __restrict__ wsc, unsigned* __restrict__ amax) {
    int gid = blockIdx.x * blockDim.x + threadIdx.x;
    if (gid == 0) *amax = 0u;   // zero-init; absmax launches after quantw on same stream
    int row = gid >> 6, lane = gid & 63;
    const float4* r4 = (const float4*)(w + (long)row * DIN);
    float4 a = r4[lane * 2];
    float4 b = r4[lane * 2 + 1];
    float m = fmaxf(fmaxf(fmaxf(fabsf(a.x), fabsf(a.y)), fabsf(a.z)),
                    fmaxf(fmaxf(fabsf(a.w), fabsf(b.x)),
                          fmaxf(fmaxf(fabsf(b.y), fabsf(b.z)), fabsf(b.w))));
#pragma unroll
    for (int off = 32; off; off >>= 1) m = fmaxf(m, __shfl_xor(m, off));
    float s = m / 127.0f;
    int lo = q8f(a.x, s) | (q8f(a.y, s) << 8) | (q8f(a.z, s) << 16) | (q8f(a.w, s) << 24);
    int hi = q8f(b.x, s) | (q8f(b.y, s) << 8) | (q8f(b.z, s) << 16) | (q8f(b.w, s) << 24);
    {
        int og = row >> 4, r = row & 15;
        int ks = lane >> 3, kq = (lane >> 1) & 3, bo = (lane & 1) * 8;
        *(int2*)(wq8 + og * 8192 + ks * 1024 + kq * 256 + r * 16 + bo) = make_int2(lo, hi);
    }
    if (lane == 0) wsc[row] = s;
}

// ---------------- Kernel 3: barrier-free per-wave GEMM, in-register x-quant, ----------------
// ---------------- og-PAIRED stores (full 128B lines per row per pair)        ----------------
// Identical to R13 except the store path: results of og and og+1 are held in
// registers and stored back-to-back, so each touched row receives a contiguous,
// temporally-adjacent 128B (one full L2->HBM line) instead of lone 64B chunks
// ~2us apart. This removes the partial-line RMW amplification (R1 137MB clean
// vs R6/R7/R10 167-179MB scattered-over-time evidence).
__global__ __launch_bounds__(256, 2) void gemm_kernel(
    const float* __restrict__ x, const char* __restrict__ wq8,
    const float* __restrict__ wsc, const float* __restrict__ bias,
    const unsigned* __restrict__ amax, float* __restrict__ out) {
    __shared__ __align__(16) float bsl[512];
    __shared__ __align__(16) float bql[512];
    const int t = threadIdx.x, lane = t & 63, wid = t >> 6;
    const float as = __uint_as_float(*amax) / 127.0f;
    const float inv_as = 1.0f / as;

    // fold quantb: two oc per thread
    {
        float s0 = as * wsc[t];
        bsl[t] = s0;
        bql[t] = rintf(bias[t] / s0) * s0;
        float s1 = as * wsc[t + 256];
        bsl[t + 256] = s1;
        bql[t + 256] = rintf(bias[t + 256] / s1) * s1;
    }
    __syncthreads();   // the only barrier

    const int gw = blockIdx.x * 4 + wid;                 // global wave id, 0..2047
    const long m0 = (long)gw * 32;
    const float* xb = x + (m0 + (lane & 15)) * DIN + (lane >> 4) * 16;
    const char* wg = wq8 + lane * 16;
    const int bo = (lane >> 4) * 4;                      // oc sub-offset
    float* outr = out + (m0 + (lane & 15)) * DOUT + bo;  // mi=0 row base

    // ---- pre-issue first w-group (L2) so the first compute doesn't stall
    v4i wfA[8], wfB[8];
#pragma unroll
    for (int ks = 0; ks < 8; ks++) wfA[ks] = *(const v4i*)(wg + ks * 1024);

    // ---- x-phase: 16 batches (mi,ks), 4 float4 each, quantize in-register
    v4i xa[2][8];
    float4 xv[3][4];
#define LOADB(B, S) { const float4* p_ = (const float4*)(xb + ((B) >> 3) * (16 * DIN) + ((B) & 7) * 64); \
        xv[S][0] = p_[0]; xv[S][1] = p_[1]; xv[S][2] = p_[2]; xv[S][3] = p_[3]; }
#define PK(v) (q8m((v).x, inv_as) | (q8m((v).y, inv_as) << 8) | \
               (q8m((v).z, inv_as) << 16) | (q8m((v).w, inv_as) << 24))
#define QUANTB(B, S) { v4i q_; \
        q_[0] = PK(xv[S][0]); q_[1] = PK(xv[S][1]); q_[2] = PK(xv[S][2]); q_[3] = PK(xv[S][3]); \
        xa[(B) >> 3][(B) & 7] = q_; }

    LOADB(0, 0)
    LOADB(1, 1)
#pragma unroll
    for (int b = 0; b < 16; b++) {
        if (b + 2 < 16) LOADB(b + 2, (b + 2) % 3)
        QUANTB(b, b % 3)
    }

    // ---- og-loop: compute og-pair, then store 4 v4f back-to-back
    // (rows r and r+16 each get one full contiguous 128B line per pair)
#define CCOMP(WF, OG, V0, V1) { \
    v4i a00, a01, a10, a11; \
    const v4i Z = {0, 0, 0, 0}; \
    a00 = __builtin_amdgcn_mfma_i32_16x16x64_i8(WF[0], xa[0][0], Z, 0, 0, 0); \
    a10 = __builtin_amdgcn_mfma_i32_16x16x64_i8(WF[0], xa[1][0], Z, 0, 0, 0); \
    a01 = __builtin_amdgcn_mfma_i32_16x16x64_i8(WF[1], xa[0][1], Z, 0, 0, 0); \
    a11 = __builtin_amdgcn_mfma_i32_16x16x64_i8(WF[1], xa[1][1], Z, 0, 0, 0); \
    _Pragma("unroll") for (int kp = 2; kp < 8; kp += 2) { \
        a00 = __builtin_amdgcn_mfma_i32_16x16x64_i8(WF[kp], xa[0][kp], a00, 0, 0, 0); \
        a10 = __builtin_amdgcn_mfma_i32_16x16x64_i8(WF[kp], xa[1][kp], a10, 0, 0, 0); \
        a01 = __builtin_amdgcn_mfma_i32_16x16x64_i8(WF[kp + 1], xa[0][kp + 1], a01, 0, 0, 0); \
        a11 = __builtin_amdgcn_mfma_i32_16x16x64_i8(WF[kp + 1], xa[1][kp + 1], a11, 0, 0, 0); } \
    v4i s0 = a00 + a01, s1 = a10 + a11; \
    float4 s4 = *(const float4*)&bsl[(OG) * 16 + bo]; \
    float4 q4 = *(const float4*)&bql[(OG) * 16 + bo]; \
    V0[0] = (float)s0[0] * s4.x + q4.x; V0[1] = (float)s0[1] * s4.y + q4.y; \
    V0[2] = (float)s0[2] * s4.z + q4.z; V0[3] = (float)s0[3] * s4.w + q4.w; \
    V1[0] = (float)s1[0] * s4.x + q4.x; V1[1] = (float)s1[1] * s4.y + q4.y; \
    V1[2] = (float)s1[2] * s4.z + q4.z; V1[3] = (float)s1[3] * s4.w + q4.w; }

    for (int og = 0; og < 32; og += 2) {
        v4f v0a, v1a, v0b, v1b;
#pragma unroll
        for (int ks = 0; ks < 8; ks++)
            wfB[ks] = *(const v4i*)(wg + (og + 1) * 8192 + ks * 1024);
        CCOMP(wfA, og, v0a, v1a)
        if (og + 2 < 32) {
#pragma unroll
            for (int ks = 0; ks < 8; ks++)
                wfA[ks] = *(const v4i*)(wg + (og + 2) * 8192 + ks * 1024);
        }
        CCOMP(wfB, og + 1, v0b, v1b)
        // 4 stores back-to-back: row r gets [og*64 .. og*64+128), row r+16 likewise
        *(v4f*)(outr + og * 16) = v0a;
        *(v4f*)(outr + og * 16 + 16) = v0b;
        *(v4f*)(outr + 16 * DOUT + og * 16) = v1a;
        *(v4f*)(outr + 16 * DOUT + og * 16 + 16) = v1b;
    }
#undef LOADB
#undef PK
#undef QUANTB
#undef CCOMP
}

extern "C" void kernel_launch(void* const* d_in, const int* in_sizes, int n_in,
                              void* d_out, int out_size, void* d_ws, size_t ws_size,
                              hipStream_t stream) {
    const float* x    = (const float*)d_in[0];
    const float* w    = (const float*)d_in[1];
    const float* bias = (const float*)d_in[2];
    float* out = (float*)d_out;
    const int M = in_sizes[0] / DIN;   // 65536

    char* ws = (char*)d_ws;
    unsigned* amax = (unsigned*)ws;
    char* wq8  = ws + 64;
    float* wsc = (float*)(wq8 + (long)DOUT * DIN);

    quantw_kernel<<<(DOUT * 64) / 256, 256, 0, stream>>>(w, wq8, wsc, amax);
    absmax_kernel<<<2048, 256, 0, stream>>>((const float4*)x, amax, in_sizes[0] / 4);
    gemm_kernel<<<M / 128, 256, 0, stream>>>(x, wq8, wsc, bias, amax, out);
}

// Round 16
// 98.689 us; speedup vs baseline: 1.2449x; 1.0194x over previous
//
#include <hip/hip_runtime.h>

#define DIN 512
#define DOUT 512

typedef int v4i __attribute__((ext_vector_type(4)));
typedef float v4f __attribute__((ext_vector_type(4)));

// exact-divide quantize (weights/bias path, matches ref bit-for-bit)
__device__ __forceinline__ int q8f(float v, float s) {
    int i = (int)rintf(v / s);
    i = i < -128 ? -128 : (i > 127 ? 127 : i);
    return i & 255;
}
// multiply-by-reciprocal quantize (activation path; flip prob ~2^-22, contribution ~0.005 << 0.0525)
__device__ __forceinline__ int q8m(float v, float inv) {
    int i = (int)rintf(v * inv);
    i = i < -128 ? -128 : (i > 127 ? 127 : i);
    return i & 255;
}

// ---------------- Kernel 1: global absmax of x ----------------
__global__ void absmax_kernel(const float4* __restrict__ x4, unsigned* __restrict__ amax, int n4) {
    float m = 0.f;
    int stride = gridDim.x * blockDim.x;
    for (int i = blockIdx.x * blockDim.x + threadIdx.x; i < n4; i += stride) {
        float4 v = x4[i];
        m = fmaxf(m, fmaxf(fmaxf(fabsf(v.x), fabsf(v.y)), fmaxf(fabsf(v.z), fabsf(v.w))));
    }
#pragma unroll
    for (int off = 32; off; off >>= 1) m = fmaxf(m, __shfl_xor(m, off));
    __shared__ float sm[4];
    int lane = threadIdx.x & 63, w = threadIdx.x >> 6;
    if (lane == 0) sm[w] = m;
    __syncthreads();
    if (threadIdx.x == 0) {
        m = fmaxf(fmaxf(sm[0], sm[1]), fmaxf(sm[2], sm[3]));
        atomicMax(amax, __float_as_uint(m));  // positive floats: uint compare == float compare
    }
}

// ---------------- Kernel 2: weight quant -> frag-linear wq8 (+ amax zero-init) ----------------
// wq8 byte(og,ks,kq,r,b) = og*8192 + ks*1024 + kq*256 + r*16 + b ==> a wave's
// A-frag (og,ks) is CONTIGUOUS 1KB at wq8 + og*8192 + ks*1024 + lane*16. (R12-validated)
__global__ void quantw_kernel(const float* __restrict__ w, char* __restrict__ wq8,
                              float* __restrict__ wsc, unsigned* __restrict__ amax) {
    int gid = blockIdx.x * blockDim.x + threadIdx.x;
    if (gid == 0) *amax = 0u;   // zero-init; absmax launches after quantw on same stream
    int row = gid >> 6, lane = gid & 63;
    const float4* r4 = (const float4*)(w + (long)row * DIN);
    float4 a = r4[lane * 2];
    float4 b = r4[lane * 2 + 1];
    float m = fmaxf(fmaxf(fmaxf(fabsf(a.x), fabsf(a.y)), fabsf(a.z)),
                    fmaxf(fmaxf(fabsf(a.w), fabsf(b.x)),
                          fmaxf(fmaxf(fabsf(b.y), fabsf(b.z)), fabsf(b.w))));
#pragma unroll
    for (int off = 32; off; off >>= 1) m = fmaxf(m, __shfl_xor(m, off));
    float s = m / 127.0f;
    int lo = q8f(a.x, s) | (q8f(a.y, s) << 8) | (q8f(a.z, s) << 16) | (q8f(a.w, s) << 24);
    int hi = q8f(b.x, s) | (q8f(b.y, s) << 8) | (q8f(b.z, s) << 16) | (q8f(b.w, s) << 24);
    {
        int og = row >> 4, r = row & 15;
        int ks = lane >> 3, kq = (lane >> 1) & 3, bo = (lane & 1) * 8;
        *(int2*)(wq8 + og * 8192 + ks * 1024 + kq * 256 + r * 16 + bo) = make_int2(lo, hi);
    }
    if (lane == 0) wsc[row] = s;
}

// ---------------- Kernel 3: barrier-free per-wave GEMM ----------------
// R15 structure + three same-mechanism fixes:
//  (1) nt paired stores: out bypasses L2 (full 128B/row per og-pair) so the
//      write stream stops evicting L2-resident wq8;
//  (2) w-prefetch depth-2 compute-blocks via 4-buffer rotation (wfA..wfD):
//      og+2/og+3 loads issue ~900cy before consumption, covering L3 slips;
//  (3) x-phase load pipeline depth 3 (xv[4], ~600cy cover).
__global__ __launch_bounds__(256, 2) void gemm_kernel(
    const float* __restrict__ x, const char* __restrict__ wq8,
    const float* __restrict__ wsc, const float* __restrict__ bias,
    const unsigned* __restrict__ amax, float* __restrict__ out) {
    __shared__ __align__(16) float bsl[512];
    __shared__ __align__(16) float bql[512];
    const int t = threadIdx.x, lane = t & 63, wid = t >> 6;
    const float as = __uint_as_float(*amax) / 127.0f;
    const float inv_as = 1.0f / as;

    // fold quantb: two oc per thread
    {
        float s0 = as * wsc[t];
        bsl[t] = s0;
        bql[t] = rintf(bias[t] / s0) * s0;
        float s1 = as * wsc[t + 256];
        bsl[t + 256] = s1;
        bql[t + 256] = rintf(bias[t + 256] / s1) * s1;
    }
    __syncthreads();   // the only barrier

    const int gw = blockIdx.x * 4 + wid;                 // global wave id, 0..2047
    const long m0 = (long)gw * 32;
    const float* xb = x + (m0 + (lane & 15)) * DIN + (lane >> 4) * 16;
    const char* wg = wq8 + lane * 16;
    const int bo = (lane >> 4) * 4;                      // oc sub-offset
    float* outr = out + (m0 + (lane & 15)) * DOUT + bo;  // mi=0 row base

    v4i wfA[8], wfB[8], wfC[8], wfD[8];
#define LDW(DST, G) { _Pragma("unroll") for (int ks = 0; ks < 8; ks++) \
        DST[ks] = *(const v4i*)(wg + (G) * 8192 + ks * 1024); }

    // pre-issue first two w-groups; they land during the long x-phase
    LDW(wfA, 0)
    LDW(wfB, 1)

    // ---- x-phase: 16 batches (mi,ks), 4 float4 each, quantize in-register, depth-3
    v4i xa[2][8];
    float4 xv[4][4];
#define LOADB(B, S) { const float4* p_ = (const float4*)(xb + ((B) >> 3) * (16 * DIN) + ((B) & 7) * 64); \
        xv[S][0] = p_[0]; xv[S][1] = p_[1]; xv[S][2] = p_[2]; xv[S][3] = p_[3]; }
#define PK(v) (q8m((v).x, inv_as) | (q8m((v).y, inv_as) << 8) | \
               (q8m((v).z, inv_as) << 16) | (q8m((v).w, inv_as) << 24))
#define QUANTB(B, S) { v4i q_; \
        q_[0] = PK(xv[S][0]); q_[1] = PK(xv[S][1]); q_[2] = PK(xv[S][2]); q_[3] = PK(xv[S][3]); \
        xa[(B) >> 3][(B) & 7] = q_; }

    LOADB(0, 0)
    LOADB(1, 1)
    LOADB(2, 2)
#pragma unroll
    for (int b = 0; b < 16; b++) {
        if (b + 3 < 16) LOADB(b + 3, (b + 3) & 3)
        QUANTB(b, b & 3)
    }

    // ---- og-loop: 4 og per iteration, 4-buffer w rotation, nt paired stores
#define CCOMP(WF, OG, V0, V1) { \
    v4i a00, a01, a10, a11; \
    const v4i Z = {0, 0, 0, 0}; \
    a00 = __builtin_amdgcn_mfma_i32_16x16x64_i8(WF[0], xa[0][0], Z, 0, 0, 0); \
    a10 = __builtin_amdgcn_mfma_i32_16x16x64_i8(WF[0], xa[1][0], Z, 0, 0, 0); \
    a01 = __builtin_amdgcn_mfma_i32_16x16x64_i8(WF[1], xa[0][1], Z, 0, 0, 0); \
    a11 = __builtin_amdgcn_mfma_i32_16x16x64_i8(WF[1], xa[1][1], Z, 0, 0, 0); \
    _Pragma("unroll") for (int kp = 2; kp < 8; kp += 2) { \
        a00 = __builtin_amdgcn_mfma_i32_16x16x64_i8(WF[kp], xa[0][kp], a00, 0, 0, 0); \
        a10 = __builtin_amdgcn_mfma_i32_16x16x64_i8(WF[kp], xa[1][kp], a10, 0, 0, 0); \
        a01 = __builtin_amdgcn_mfma_i32_16x16x64_i8(WF[kp + 1], xa[0][kp + 1], a01, 0, 0, 0); \
        a11 = __builtin_amdgcn_mfma_i32_16x16x64_i8(WF[kp + 1], xa[1][kp + 1], a11, 0, 0, 0); } \
    v4i s0 = a00 + a01, s1 = a10 + a11; \
    float4 s4 = *(const float4*)&bsl[(OG) * 16 + bo]; \
    float4 q4 = *(const float4*)&bql[(OG) * 16 + bo]; \
    V0[0] = (float)s0[0] * s4.x + q4.x; V0[1] = (float)s0[1] * s4.y + q4.y; \
    V0[2] = (float)s0[2] * s4.z + q4.z; V0[3] = (float)s0[3] * s4.w + q4.w; \
    V1[0] = (float)s1[0] * s4.x + q4.x; V1[1] = (float)s1[1] * s4.y + q4.y; \
    V1[2] = (float)s1[2] * s4.z + q4.z; V1[3] = (float)s1[3] * s4.w + q4.w; }
#define NTST(OG, V0A, V0B, V1A, V1B) { \
    __builtin_nontemporal_store(V0A, (v4f*)(outr + (OG) * 16)); \
    __builtin_nontemporal_store(V0B, (v4f*)(outr + (OG) * 16 + 16)); \
    __builtin_nontemporal_store(V1A, (v4f*)(outr + 16 * DOUT + (OG) * 16)); \
    __builtin_nontemporal_store(V1B, (v4f*)(outr + 16 * DOUT + (OG) * 16 + 16)); }

#pragma unroll 1
    for (int og = 0; og < 32; og += 4) {
        v4f v0a, v1a, v0b, v1b;
        // pair (og, og+1) from wfA/wfB; prefetch og+2/og+3 into wfC/wfD
        LDW(wfC, og + 2)
        CCOMP(wfA, og, v0a, v1a)
        LDW(wfD, og + 3)
        CCOMP(wfB, og + 1, v0b, v1b)
        NTST(og, v0a, v0b, v1a, v1b)
        // pair (og+2, og+3) from wfC/wfD; prefetch og+4/og+5 into wfA/wfB
        if (og + 4 < 32) LDW(wfA, og + 4)
        CCOMP(wfC, og + 2, v0a, v1a)
        if (og + 5 < 32) LDW(wfB, og + 5)
        CCOMP(wfD, og + 3, v0b, v1b)
        NTST(og + 2, v0a, v0b, v1a, v1b)
    }
#undef LDW
#undef LOADB
#undef PK
#undef QUANTB
#undef CCOMP
#undef NTST
}

extern "C" void kernel_launch(void* const* d_in, const int* in_sizes, int n_in,
                              void* d_out, int out_size, void* d_ws, size_t ws_size,
                              hipStream_t stream) {
    const float* x    = (const float*)d_in[0];
    const float* w    = (const float*)d_in[1];
    const float* bias = (const float*)d_in[2];
    float* out = (float*)d_out;
    const int M = in_sizes[0] / DIN;   // 65536

    char* ws = (char*)d_ws;
    unsigned* amax = (unsigned*)ws;
    char* wq8  = ws + 64;
    float* wsc = (float*)(wq8 + (long)DOUT * DIN);

    quantw_kernel<<<(DOUT * 64) / 256, 256, 0, stream>>>(w, wq8, wsc, amax);
    absmax_kernel<<<2048, 256, 0, stream>>>((const float4*)x, amax, in_sizes[0] / 4);
    gemm_kernel<<<M / 128, 256, 0, stream>>>(x, wq8, wsc, bias, amax, out);
}